// Round 15
// baseline (228.669 us; speedup 1.0000x reference)
//
#include <hip/hip_runtime.h>
#include <hip/hip_bf16.h>
#include <cstdint>
#include <cstddef>

#define B_    4
#define T_    2048
#define DIN_  1024
#define DEMB_ 1024
#define H_    16
#define HD_   64
#define M_    8192        // B_*T_
#define NQKV_ 3072        // 3*DEMB_

// Q pre-scale: 1/sqrt(HD) * log2(e)  (softmax done in exp2 domain)
#define QSCALE 0.18033688011112042f

typedef __bf16 bf16_t;
typedef __bf16 bf16x8 __attribute__((ext_vector_type(8)));
typedef __bf16 bf16x4 __attribute__((ext_vector_type(4)));
typedef float  f32x4  __attribute__((ext_vector_type(4)));
typedef float  f32x16 __attribute__((ext_vector_type(16)));
typedef unsigned int u32x4 __attribute__((ext_vector_type(4)));

__device__ __forceinline__ bf16_t tob(float f) {
  __hip_bfloat16 h = __float2bfloat16(f);
  return __builtin_bit_cast(bf16_t, h);
}

__device__ __forceinline__ f32x4 mfma16(bf16x8 a, bf16x8 b, f32x4 c) {
  return __builtin_amdgcn_mfma_f32_16x16x32_bf16(a, b, c, 0, 0, 0);
}
__device__ __forceinline__ f32x16 mfma32(bf16x8 a, bf16x8 b, f32x16 c) {
  return __builtin_amdgcn_mfma_f32_32x32x16_bf16(a, b, c, 0, 0, 0);
}

__device__ __forceinline__ float fexp2(float x) {
#if __has_builtin(__builtin_amdgcn_exp2f)
  return __builtin_amdgcn_exp2f(x);
#else
  return exp2f(x);
#endif
}

// packed f32x2 -> bf16x2 (RNE) in one VALU op (T12 primitive)
__device__ __forceinline__ unsigned pk2(float lo, float hi) {
  unsigned r;
  asm("v_cvt_pk_bf16_f32 %0, %1, %2" : "=v"(r) : "v"(lo), "v"(hi));
  return r;
}

// lane[i] <-> lane[i+32] half-swap of two regs in ONE instruction (T12)
__device__ __forceinline__ void plswap(unsigned& a, unsigned& b) {
  asm("v_permlane32_swap_b32 %0, %1" : "+v"(a), "+v"(b));
}

__device__ __forceinline__ void gload16(const void* g, void* l) {
  __builtin_amdgcn_global_load_lds((const __attribute__((address_space(1))) void*)g,
                                   (__attribute__((address_space(3))) void*)l, 16, 0, 0);
}

// ---------------- fused fp32 -> bf16 cast for x, w_qkv, w_o (one launch) ----------------
__global__ __launch_bounds__(256) void cast3_kernel(const float* __restrict__ a, bf16_t* __restrict__ ao,
                                                    const float* __restrict__ b, bf16_t* __restrict__ bo,
                                                    const float* __restrict__ c, bf16_t* __restrict__ co) {
  constexpr int na4 = M_ * DIN_ / 4;        // 2,097,152
  constexpr int nb4 = NQKV_ * DIN_ / 4;     //   786,432
  const int i = blockIdx.x * 256 + threadIdx.x;
  const float* src; bf16_t* dst; int off;
  if (i < na4)            { src = a; dst = ao; off = i; }
  else if (i < na4 + nb4) { src = b; dst = bo; off = i - na4; }
  else                    { src = c; dst = co; off = i - na4 - nb4; }
  float4 v = ((const float4*)src)[off];
  bf16x4 o;
  o[0] = tob(v.x); o[1] = tob(v.y); o[2] = tob(v.z); o[3] = tob(v.w);
  ((bf16x4*)dst)[off] = o;
}

// ---------------- GEMM1: 128x128 tile, BK=64, single-buffer, row-XOR swizzled LDS ----------------
__global__ __launch_bounds__(256, 3) void gemm_qkv_kernel(const bf16_t* __restrict__ A,
                                                          const bf16_t* __restrict__ Bm,
                                                          bf16_t* __restrict__ qb,
                                                          bf16_t* __restrict__ kb,
                                                          bf16_t* __restrict__ vbT) {
  constexpr int K = DIN_;
  __shared__ __align__(16) bf16_t As[128 * 64];
  __shared__ __align__(16) bf16_t Bs[128 * 64];
  const int tid = threadIdx.x, w = tid >> 6, l = tid & 63;
  const int lh = l >> 4, lr = l & 15;
  const int m0 = blockIdx.y * 128, n0 = blockIdx.x * 128;
  const int ar0 = (w >> 1) * 64, bc0 = (w & 1) * 64;
  f32x4 acc[4][4] = {};
  for (int k0 = 0; k0 < K; k0 += 64) {
#pragma unroll
    for (int i = 0; i < 4; ++i) {
      const int jx = i * 256 + tid;                     // 16B unit index 0..1023
      const int row = jx >> 3, us = (jx & 7) ^ (row & 7);  // pre-swizzled SOURCE col
      gload16(A  + (size_t)(m0 + row) * K + k0 + us * 8, (char*)As + (size_t)(i * 256 + w * 64) * 16);
      gload16(Bm + (size_t)(n0 + row) * K + k0 + us * 8, (char*)Bs + (size_t)(i * 256 + w * 64) * 16);
    }
    __syncthreads();
#pragma unroll
    for (int kk = 0; kk < 2; ++kk) {
      bf16x8 af[4], bfv[4];
#pragma unroll
      for (int mi = 0; mi < 4; ++mi) {
        const int r = ar0 + mi * 16 + lr;
        af[mi] = *(const bf16x8*)&As[r * 64 + (((kk * 4 + lh) ^ (r & 7)) * 8)];
      }
#pragma unroll
      for (int ni = 0; ni < 4; ++ni) {
        const int r = bc0 + ni * 16 + lr;
        bfv[ni] = *(const bf16x8*)&Bs[r * 64 + (((kk * 4 + lh) ^ (r & 7)) * 8)];
      }
      __builtin_amdgcn_s_setprio(1);
#pragma unroll
      for (int mi = 0; mi < 4; ++mi)
#pragma unroll
        for (int ni = 0; ni < 4; ++ni)
          acc[mi][ni] = mfma16(af[mi], bfv[ni], acc[mi][ni]);
      __builtin_amdgcn_s_setprio(0);
    }
    __syncthreads();
  }
  // epilogue: Q/K scalar (row-major dest), V^T packed bf16x4 (4 consecutive t per d-row).
#pragma unroll
  for (int mi = 0; mi < 4; ++mi) {
    const int gm0 = m0 + ar0 + mi * 16 + lh * 4;
    const int bb = gm0 >> 11, t0 = gm0 & (T_ - 1);
#pragma unroll
    for (int ni = 0; ni < 4; ++ni) {
      const int gn = n0 + bc0 + ni * 16 + lr;
      const int h = gn / 192, s = gn - h * 192;
      const size_t bhb = (size_t)bb * H_ + h;
      if (s < 64) {
#pragma unroll
        for (int r = 0; r < 4; ++r)
          qb[(bhb * T_ + t0 + r) * HD_ + s] = tob(acc[mi][ni][r] * QSCALE);
      } else if (s < 128) {
#pragma unroll
        for (int r = 0; r < 4; ++r)
          kb[(bhb * T_ + t0 + r) * HD_ + s - 64] = tob(acc[mi][ni][r]);
      } else {
        bf16x4 pv;
#pragma unroll
        for (int r = 0; r < 4; ++r) pv[r] = tob(acc[mi][ni][r]);
        *(bf16x4*)&vbT[(bhb * HD_ + (s - 128)) * T_ + t0] = pv;
      }
    }
  }
}

// ---------------- flash attention v3: direct-from-global K/V (no LDS, no barriers) ----------------
// K/V for a (b,h) is 512 KB; 8 bh per XCD = 4 MB = L2-resident -> LDS staging was
// pure overhead (m169 lesson). 2048 uniform 1-wave blocks: 32 strip-pairs {p,63-p}
// (32 q-rows each, 33 tile-iters total) x 64 bh; bh low bits = id&7 -> same-bh
// blocks share an XCD's L2. Fully independent waves, zero synchronization.
__global__ __launch_bounds__(64) void attn3_kernel(const bf16_t* __restrict__ qg,
                                                   const bf16_t* __restrict__ kg,
                                                   const bf16_t* __restrict__ vtg,
                                                   bf16_t* __restrict__ ob) {
  const int id = blockIdx.x;
  const int pp = (id >> 3) & 31;
  const int bh = (id & 7) | ((id >> 8) << 3);
  const int l = threadIdx.x;
  const int q5 = l & 31, hi = l >> 5, hi8 = hi * 8;
  const bf16_t* Qg  = qg  + (size_t)bh * T_ * HD_;
  const bf16_t* Kg  = kg  + (size_t)bh * T_ * HD_;
  const bf16_t* Vtg = vtg + (size_t)bh * HD_ * T_;

  for (int ph = 0; ph < 2; ++ph) {
    const int st = ph ? (63 - pp) : pp;          // 32-row q-strip index
    const int ktmax = (st >> 1) + 1;
    const int myKt  = st >> 1;
    const int thrD  = st * 32 + q5 - myKt * 64 - 4 * hi;

    bf16x8 bq[4];
#pragma unroll
    for (int s = 0; s < 4; ++s)
      bq[s] = *(const bf16x8*)&Qg[(size_t)(st * 32 + q5) * HD_ + s * 16 + hi8];

    f32x16 o0 = {}, o1 = {};
    float lrun = 0.f;

    for (int kt = 0; kt < ktmax; ++kt) {
      // ---- K fragments from global + QK^T (swapped): col = q ----
      f32x16 sA = {}, sB = {};
#pragma unroll
      for (int s = 0; s < 4; ++s) {
        bf16x8 a0 = *(const bf16x8*)&Kg[(size_t)(kt * 64 + q5)      * HD_ + s * 16 + hi8];
        bf16x8 a1 = *(const bf16x8*)&Kg[(size_t)(kt * 64 + q5 + 32) * HD_ + s * 16 + hi8];
        sA = mfma32(a0, bq[s], sA);
        sB = mfma32(a1, bq[s], sB);
      }
      // ---- V^T fragments from global (issued early; independent of S) ----
      bf16x8 avA[4], avB[4];
#pragma unroll
      for (int t32 = 0; t32 < 2; ++t32)
#pragma unroll
        for (int s2 = 0; s2 < 2; ++s2) {
          const int kvo = kt * 64 + t32 * 32 + s2 * 16 + hi8;
          avA[t32 * 2 + s2] = *(const bf16x8*)&Vtg[(size_t)(q5)      * T_ + kvo];
          avB[t32 * 2 + s2] = *(const bf16x8*)&Vtg[(size_t)(q5 + 32) * T_ + kvo];
        }
      // ---- causal mask (diag tile only) ----
      if (kt == myKt) {
#pragma unroll
        for (int r = 0; r < 16; ++r) {
          const int kvc = (r & 3) + 8 * (r >> 2);
          sA[r] = (kvc      > thrD) ? -1e30f : sA[r];
          sB[r] = (kvc + 32 > thrD) ? -1e30f : sB[r];
        }
      }
      // ---- static-max softmax: P = exp2(S), l += sum(P) ----
      float l0 = 0.f, l1 = 0.f, l2 = 0.f, l3 = 0.f;
#pragma unroll
      for (int r = 0; r < 16; r += 4) {
        sA[r]     = fexp2(sA[r]);     sB[r]     = fexp2(sB[r]);
        sA[r + 1] = fexp2(sA[r + 1]); sB[r + 1] = fexp2(sB[r + 1]);
        sA[r + 2] = fexp2(sA[r + 2]); sB[r + 2] = fexp2(sB[r + 2]);
        sA[r + 3] = fexp2(sA[r + 3]); sB[r + 3] = fexp2(sB[r + 3]);
        l0 += sA[r]     + sB[r];
        l1 += sA[r + 1] + sB[r + 1];
        l2 += sA[r + 2] + sB[r + 2];
        l3 += sA[r + 3] + sB[r + 3];
      }
      lrun += (l0 + l1) + (l2 + l3);
      // ---- P -> bf16 B-frags (cvt_pk + permlane32_swap) and PV ----
#pragma unroll
      for (int t32 = 0; t32 < 2; ++t32) {
        const f32x16& p = t32 ? sB : sA;
#pragma unroll
        for (int s2 = 0; s2 < 2; ++s2) {
          unsigned a0 = pk2(p[8 * s2 + 0], p[8 * s2 + 1]);
          unsigned a1 = pk2(p[8 * s2 + 2], p[8 * s2 + 3]);
          unsigned b0 = pk2(p[8 * s2 + 4], p[8 * s2 + 5]);
          unsigned b1 = pk2(p[8 * s2 + 6], p[8 * s2 + 7]);
          plswap(a0, b0);   // {fw.x, fw.z}
          plswap(a1, b1);   // {fw.y, fw.w}
          u32x4 fw = {a0, a1, b0, b1};
          const bf16x8 pb = __builtin_bit_cast(bf16x8, fw);
          o0 = mfma32(avA[t32 * 2 + s2], pb, o0);
          o1 = mfma32(avB[t32 * 2 + s2], pb, o1);
        }
      }
    }

    const float ltot = lrun + __shfl_xor(lrun, 32);
    const float inv = 1.f / ltot;
    const size_t rowb = ((size_t)(bh >> 4) * T_ + st * 32 + q5) * DEMB_ + (bh & 15) * HD_;
#pragma unroll
    for (int g = 0; g < 4; ++g) {
      bf16x4 st0, st1;
#pragma unroll
      for (int j = 0; j < 4; ++j) {
        st0[j] = tob(o0[4 * g + j] * inv);
        st1[j] = tob(o1[4 * g + j] * inv);
      }
      *(bf16x4*)&ob[rowb + 8 * g + 4 * hi]      = st0;
      *(bf16x4*)&ob[rowb + 8 * g + 4 * hi + 32] = st1;
    }
  }
}

// ---------------- GEMM2: 128x128 tile, BK=64, single-buffer, row-XOR swizzled LDS ----------------
__global__ __launch_bounds__(256, 3) void gemm_out_kernel(const bf16_t* __restrict__ A,
                                                          const bf16_t* __restrict__ Bm,
                                                          const float* __restrict__ bo,
                                                          float* __restrict__ out) {
  constexpr int K = DEMB_;
  __shared__ __align__(16) bf16_t As[128 * 64];
  __shared__ __align__(16) bf16_t Bs[128 * 64];
  const int tid = threadIdx.x, w = tid >> 6, l = tid & 63;
  const int lh = l >> 4, lr = l & 15;
  const int m0 = blockIdx.y * 128, n0 = blockIdx.x * 128;
  const int ar0 = (w >> 1) * 64, bc0 = (w & 1) * 64;
  f32x4 acc[4][4] = {};
  for (int k0 = 0; k0 < K; k0 += 64) {
#pragma unroll
    for (int i = 0; i < 4; ++i) {
      const int jx = i * 256 + tid;
      const int row = jx >> 3, us = (jx & 7) ^ (row & 7);
      gload16(A  + (size_t)(m0 + row) * K + k0 + us * 8, (char*)As + (size_t)(i * 256 + w * 64) * 16);
      gload16(Bm + (size_t)(n0 + row) * K + k0 + us * 8, (char*)Bs + (size_t)(i * 256 + w * 64) * 16);
    }
    __syncthreads();
#pragma unroll
    for (int kk = 0; kk < 2; ++kk) {
      bf16x8 af[4], bfv[4];
#pragma unroll
      for (int mi = 0; mi < 4; ++mi) {
        const int r = ar0 + mi * 16 + lr;
        af[mi] = *(const bf16x8*)&As[r * 64 + (((kk * 4 + lh) ^ (r & 7)) * 8)];
      }
#pragma unroll
      for (int ni = 0; ni < 4; ++ni) {
        const int r = bc0 + ni * 16 + lr;
        bfv[ni] = *(const bf16x8*)&Bs[r * 64 + (((kk * 4 + lh) ^ (r & 7)) * 8)];
      }
      __builtin_amdgcn_s_setprio(1);
#pragma unroll
      for (int mi = 0; mi < 4; ++mi)
#pragma unroll
        for (int ni = 0; ni < 4; ++ni)
          acc[mi][ni] = mfma16(af[mi], bfv[ni], acc[mi][ni]);
      __builtin_amdgcn_s_setprio(0);
    }
    __syncthreads();
  }
#pragma unroll
  for (int mi = 0; mi < 4; ++mi) {
#pragma unroll
    for (int r = 0; r < 4; ++r) {
      const int gm = m0 + ar0 + mi * 16 + lh * 4 + r;
#pragma unroll
      for (int ni = 0; ni < 4; ++ni) {
        const int gn = n0 + bc0 + ni * 16 + lr;
        out[(size_t)gm * DEMB_ + gn] = acc[mi][ni][r] + bo[gn];
      }
    }
  }
}

extern "C" void kernel_launch(void* const* d_in, const int* in_sizes, int n_in,
                              void* d_out, int out_size, void* d_ws, size_t ws_size,
                              hipStream_t stream) {
  (void)in_sizes; (void)n_in; (void)out_size; (void)ws_size;
  const float* x     = (const float*)d_in[0];
  const float* w_qkv = (const float*)d_in[1];
  const float* w_o   = (const float*)d_in[2];
  const float* b_o   = (const float*)d_in[3];
  float* out = (float*)d_out;

  // Round-1-proven 75.5 MB workspace layout; vbuf holds V^T [B,H,64,T].
  char* p = (char*)d_ws;
  bf16_t* xb    = (bf16_t*)p; p += (size_t)M_ * DIN_ * 2;
  bf16_t* wqkvb = (bf16_t*)p; p += (size_t)NQKV_ * DIN_ * 2;
  bf16_t* wob   = (bf16_t*)p; p += (size_t)DEMB_ * DEMB_ * 2;
  bf16_t* qbuf  = (bf16_t*)p; p += (size_t)B_ * H_ * T_ * HD_ * 2;
  bf16_t* kbuf  = (bf16_t*)p; p += (size_t)B_ * H_ * T_ * HD_ * 2;
  bf16_t* vbuf  = (bf16_t*)p; p += (size_t)B_ * H_ * T_ * HD_ * 2;
  bf16_t* attnb = xb;    // x dead after gemm1

  constexpr int CAST_BLOCKS = (M_ * DIN_ + NQKV_ * DIN_ + DEMB_ * DEMB_) / 1024;  // 12288
  cast3_kernel<<<CAST_BLOCKS, 256, 0, stream>>>(x, xb, w_qkv, wqkvb, w_o, wob);
  gemm_qkv_kernel<<<dim3(NQKV_ / 128, M_ / 128), 256, 0, stream>>>(xb, wqkvb, qbuf, kbuf, vbuf);
  attn3_kernel<<<2048, 64, 0, stream>>>(qbuf, kbuf, vbuf, attnb);
  gemm_out_kernel<<<dim3(DEMB_ / 128, M_ / 128), 256, 0, stream>>>(attnb, wob, b_o, out);
}

// Round 16
// 152.966 us; speedup vs baseline: 1.4949x; 1.4949x over previous
//
#include <hip/hip_runtime.h>
#include <hip/hip_bf16.h>
#include <cstdint>
#include <cstddef>

#define B_    4
#define T_    2048
#define DIN_  1024
#define DEMB_ 1024
#define H_    16
#define HD_   64
#define M_    8192        // B_*T_
#define NQKV_ 3072        // 3*DEMB_

// Q pre-scale: 1/sqrt(HD) * log2(e)  (softmax done in exp2 domain)
#define QSCALE 0.18033688011112042f

typedef __bf16 bf16_t;
typedef __bf16 bf16x8 __attribute__((ext_vector_type(8)));
typedef __bf16 bf16x4 __attribute__((ext_vector_type(4)));
typedef float  f32x4  __attribute__((ext_vector_type(4)));
typedef float  f32x16 __attribute__((ext_vector_type(16)));
typedef unsigned int u32x4 __attribute__((ext_vector_type(4)));

__device__ __forceinline__ bf16_t tob(float f) {
  __hip_bfloat16 h = __float2bfloat16(f);
  return __builtin_bit_cast(bf16_t, h);
}

__device__ __forceinline__ f32x4 mfma16(bf16x8 a, bf16x8 b, f32x4 c) {
  return __builtin_amdgcn_mfma_f32_16x16x32_bf16(a, b, c, 0, 0, 0);
}
__device__ __forceinline__ f32x16 mfma32(bf16x8 a, bf16x8 b, f32x16 c) {
  return __builtin_amdgcn_mfma_f32_32x32x16_bf16(a, b, c, 0, 0, 0);
}

__device__ __forceinline__ float fexp2(float x) {
#if __has_builtin(__builtin_amdgcn_exp2f)
  return __builtin_amdgcn_exp2f(x);
#else
  return exp2f(x);
#endif
}

// packed f32x2 -> bf16x2 (RNE) in one VALU op (T12 primitive)
__device__ __forceinline__ unsigned pk2(float lo, float hi) {
  unsigned r;
  asm("v_cvt_pk_bf16_f32 %0, %1, %2" : "=v"(r) : "v"(lo), "v"(hi));
  return r;
}

// lane[i] <-> lane[i+32] half-swap of two regs in ONE instruction (T12)
__device__ __forceinline__ void plswap(unsigned& a, unsigned& b) {
  asm("v_permlane32_swap_b32 %0, %1" : "+v"(a), "+v"(b));
}

__device__ __forceinline__ void gload16(const void* g, void* l) {
  __builtin_amdgcn_global_load_lds((const __attribute__((address_space(1))) void*)g,
                                   (__attribute__((address_space(3))) void*)l, 16, 0, 0);
}

// ---------------- fused fp32 -> bf16 cast for x, w_qkv, w_o (one launch) ----------------
__global__ __launch_bounds__(256) void cast3_kernel(const float* __restrict__ a, bf16_t* __restrict__ ao,
                                                    const float* __restrict__ b, bf16_t* __restrict__ bo,
                                                    const float* __restrict__ c, bf16_t* __restrict__ co) {
  constexpr int na4 = M_ * DIN_ / 4;        // 2,097,152
  constexpr int nb4 = NQKV_ * DIN_ / 4;     //   786,432
  const int i = blockIdx.x * 256 + threadIdx.x;
  const float* src; bf16_t* dst; int off;
  if (i < na4)            { src = a; dst = ao; off = i; }
  else if (i < na4 + nb4) { src = b; dst = bo; off = i - na4; }
  else                    { src = c; dst = co; off = i - na4 - nb4; }
  float4 v = ((const float4*)src)[off];
  bf16x4 o;
  o[0] = tob(v.x); o[1] = tob(v.y); o[2] = tob(v.z); o[3] = tob(v.w);
  ((bf16x4*)dst)[off] = o;
}

// ---------------- GEMM1: 128x128 tile, BK=64, single-buffer, row-XOR swizzled LDS ----------------
__global__ __launch_bounds__(256, 3) void gemm_qkv_kernel(const bf16_t* __restrict__ A,
                                                          const bf16_t* __restrict__ Bm,
                                                          bf16_t* __restrict__ qb,
                                                          bf16_t* __restrict__ kb,
                                                          bf16_t* __restrict__ vbT) {
  constexpr int K = DIN_;
  __shared__ __align__(16) bf16_t As[128 * 64];
  __shared__ __align__(16) bf16_t Bs[128 * 64];
  const int tid = threadIdx.x, w = tid >> 6, l = tid & 63;
  const int lh = l >> 4, lr = l & 15;
  const int m0 = blockIdx.y * 128, n0 = blockIdx.x * 128;
  const int ar0 = (w >> 1) * 64, bc0 = (w & 1) * 64;
  f32x4 acc[4][4] = {};
  for (int k0 = 0; k0 < K; k0 += 64) {
#pragma unroll
    for (int i = 0; i < 4; ++i) {
      const int jx = i * 256 + tid;                     // 16B unit index 0..1023
      const int row = jx >> 3, us = (jx & 7) ^ (row & 7);  // pre-swizzled SOURCE col
      gload16(A  + (size_t)(m0 + row) * K + k0 + us * 8, (char*)As + (size_t)(i * 256 + w * 64) * 16);
      gload16(Bm + (size_t)(n0 + row) * K + k0 + us * 8, (char*)Bs + (size_t)(i * 256 + w * 64) * 16);
    }
    __syncthreads();
#pragma unroll
    for (int kk = 0; kk < 2; ++kk) {
      bf16x8 af[4], bfv[4];
#pragma unroll
      for (int mi = 0; mi < 4; ++mi) {
        const int r = ar0 + mi * 16 + lr;
        af[mi] = *(const bf16x8*)&As[r * 64 + (((kk * 4 + lh) ^ (r & 7)) * 8)];
      }
#pragma unroll
      for (int ni = 0; ni < 4; ++ni) {
        const int r = bc0 + ni * 16 + lr;
        bfv[ni] = *(const bf16x8*)&Bs[r * 64 + (((kk * 4 + lh) ^ (r & 7)) * 8)];
      }
      __builtin_amdgcn_s_setprio(1);
#pragma unroll
      for (int mi = 0; mi < 4; ++mi)
#pragma unroll
        for (int ni = 0; ni < 4; ++ni)
          acc[mi][ni] = mfma16(af[mi], bfv[ni], acc[mi][ni]);
      __builtin_amdgcn_s_setprio(0);
    }
    __syncthreads();
  }
  // epilogue: Q/K scalar (row-major dest), V^T packed bf16x4 (4 consecutive t per d-row).
#pragma unroll
  for (int mi = 0; mi < 4; ++mi) {
    const int gm0 = m0 + ar0 + mi * 16 + lh * 4;
    const int bb = gm0 >> 11, t0 = gm0 & (T_ - 1);
#pragma unroll
    for (int ni = 0; ni < 4; ++ni) {
      const int gn = n0 + bc0 + ni * 16 + lr;
      const int h = gn / 192, s = gn - h * 192;
      const size_t bhb = (size_t)bb * H_ + h;
      if (s < 64) {
#pragma unroll
        for (int r = 0; r < 4; ++r)
          qb[(bhb * T_ + t0 + r) * HD_ + s] = tob(acc[mi][ni][r] * QSCALE);
      } else if (s < 128) {
#pragma unroll
        for (int r = 0; r < 4; ++r)
          kb[(bhb * T_ + t0 + r) * HD_ + s - 64] = tob(acc[mi][ni][r]);
      } else {
        bf16x4 pv;
#pragma unroll
        for (int r = 0; r < 4; ++r) pv[r] = tob(acc[mi][ni][r]);
        *(bf16x4*)&vbT[(bhb * HD_ + (s - 128)) * T_ + t0] = pv;
      }
    }
  }
}

// ---------------- flash attention: swapped-QK 32x32, KVBLK=128 (r11 transform) ----------------
// 512 blocks: 8 x-pairs x 64 bh; block q-tiles {x, 15-x} of 128 rows -> 17 staging
// iters (uniform). Per iter: 32 MFMA/wave between barriers (2x the KVBLK=64 version),
// barriers halved. LDS 70 KB -> 2 blocks/CU (unchanged).
__global__ __launch_bounds__(256, 2) void attn2_kernel(const bf16_t* __restrict__ qg,
                                                       const bf16_t* __restrict__ kg,
                                                       const bf16_t* __restrict__ vtg,
                                                       bf16_t* __restrict__ ob) {
  __shared__ __align__(16) bf16_t Kl[2][128 * 72];  // [kv][d], pad 72
  __shared__ __align__(16) bf16_t Vl[2][64 * 136];  // [d][kv], pad 136
  const int id = blockIdx.x;
  const int x  = (id >> 3) & 7;
  const int bh = (id & 7) | ((id >> 6) << 3);       // same-bh blocks share an XCD
  const int tid = threadIdx.x, w = tid >> 6, l = tid & 63;
  const int q5 = l & 31, hi = l >> 5, hi8 = hi * 8;
  const int srow = tid >> 3, scol = (tid & 7) * 8;  // staging base: 32 rows x 64 cols
  const bf16_t* Qg  = qg  + (size_t)bh * T_ * HD_;
  const bf16_t* Kg  = kg  + (size_t)bh * T_ * HD_;
  const bf16_t* Vtg = vtg + (size_t)bh * HD_ * T_;

  for (int ph = 0; ph < 2; ++ph) {
    const int qt = ph ? (15 - x) : x;                // 128-row q-tile index
    const int qb = qt * 128 + w * 32;
    const int thrD = w * 32 + q5 - 4 * hi;           // local diag col for this wave

    bf16x8 bq[4];
#pragma unroll
    for (int s = 0; s < 4; ++s)
      bq[s] = *(const bf16x8*)&Qg[(size_t)(qb + q5) * HD_ + s * 16 + hi8];

    f32x16 o0 = {}, o1 = {};
    float lrun = 0.f;

    // prologue: stage tile 0 (K: 4 rows/thread; V^T: 2 rows x 2 col-halves/thread)
    {
#pragma unroll
      for (int j = 0; j < 4; ++j)
        *(bf16x8*)&Kl[0][(srow + 32 * j) * 72 + scol] =
            *(const bf16x8*)&Kg[(size_t)(srow + 32 * j) * HD_ + scol];
#pragma unroll
      for (int j = 0; j < 2; ++j)
#pragma unroll
        for (int k = 0; k < 2; ++k)
          *(bf16x8*)&Vl[0][(srow + 32 * j) * 136 + scol + 64 * k] =
              *(const bf16x8*)&Vtg[(size_t)(srow + 32 * j) * T_ + scol + 64 * k];
    }
    __syncthreads();
    int cur = 0;

    for (int kt = 0; kt <= qt; ++kt) {
      const bool more = (kt < qt);
      bf16x8 nk[4], nv[4];
      if (more) {  // issue next-tile loads early (hide HBM/L2 under compute)
#pragma unroll
        for (int j = 0; j < 4; ++j)
          nk[j] = *(const bf16x8*)&Kg[(size_t)((kt + 1) * 128 + srow + 32 * j) * HD_ + scol];
#pragma unroll
        for (int j = 0; j < 2; ++j)
#pragma unroll
          for (int k = 0; k < 2; ++k)
            nv[j * 2 + k] = *(const bf16x8*)&Vtg[(size_t)(srow + 32 * j) * T_ + (kt + 1) * 128 + scol + 64 * k];
      }
      // ---- QK^T (swapped) over 128 kv: s0..s3 = S^T sub-blocks, col = q ----
      f32x16 s0 = {}, s1 = {}, s2 = {}, s3 = {};
      __builtin_amdgcn_s_setprio(1);
#pragma unroll
      for (int ss = 0; ss < 4; ++ss) {
        bf16x8 a0 = *(const bf16x8*)&Kl[cur][(q5)      * 72 + ss * 16 + hi8];
        bf16x8 a1 = *(const bf16x8*)&Kl[cur][(q5 + 32) * 72 + ss * 16 + hi8];
        bf16x8 a2 = *(const bf16x8*)&Kl[cur][(q5 + 64) * 72 + ss * 16 + hi8];
        bf16x8 a3 = *(const bf16x8*)&Kl[cur][(q5 + 96) * 72 + ss * 16 + hi8];
        s0 = mfma32(a0, bq[ss], s0);
        s1 = mfma32(a1, bq[ss], s1);
        s2 = mfma32(a2, bq[ss], s2);
        s3 = mfma32(a3, bq[ss], s3);
      }
      __builtin_amdgcn_s_setprio(0);
      // ---- causal mask (diag tile only) ----
      if (kt == qt) {
#pragma unroll
        for (int r = 0; r < 16; ++r) {
          const int kvc = (r & 3) + 8 * (r >> 2);
          s0[r] = (kvc      > thrD) ? -1e30f : s0[r];
          s1[r] = (kvc + 32 > thrD) ? -1e30f : s1[r];
          s2[r] = (kvc + 64 > thrD) ? -1e30f : s2[r];
          s3[r] = (kvc + 96 > thrD) ? -1e30f : s3[r];
        }
      }
      // ---- static-max softmax: P = exp2(S), l += sum(P) ----
      float l0 = 0.f, l1 = 0.f;
#pragma unroll
      for (int r = 0; r < 16; ++r) {
        s0[r] = fexp2(s0[r]); s1[r] = fexp2(s1[r]);
        s2[r] = fexp2(s2[r]); s3[r] = fexp2(s3[r]);
        l0 += s0[r] + s1[r];
        l1 += s2[r] + s3[r];
      }
      lrun += l0 + l1;
      // ---- P -> bf16 B-frags (cvt_pk + permlane32_swap) and PV ----
#pragma unroll
      for (int t32 = 0; t32 < 4; ++t32) {
        const f32x16& p = (t32 == 0) ? s0 : (t32 == 1) ? s1 : (t32 == 2) ? s2 : s3;
#pragma unroll
        for (int sq = 0; sq < 2; ++sq) {
          unsigned a0 = pk2(p[8 * sq + 0], p[8 * sq + 1]);
          unsigned a1 = pk2(p[8 * sq + 2], p[8 * sq + 3]);
          unsigned b0 = pk2(p[8 * sq + 4], p[8 * sq + 5]);
          unsigned b1 = pk2(p[8 * sq + 6], p[8 * sq + 7]);
          plswap(a0, b0);   // {fw.x, fw.z}
          plswap(a1, b1);   // {fw.y, fw.w}
          u32x4 fw = {a0, a1, b0, b1};
          const bf16x8 pb = __builtin_bit_cast(bf16x8, fw);
          const int kvo = t32 * 32 + sq * 16 + hi8;
          bf16x8 av0 = *(const bf16x8*)&Vl[cur][(q5)      * 136 + kvo];
          bf16x8 av1 = *(const bf16x8*)&Vl[cur][(q5 + 32) * 136 + kvo];
          __builtin_amdgcn_s_setprio(1);
          o0 = mfma32(av0, pb, o0);
          o1 = mfma32(av1, pb, o1);
          __builtin_amdgcn_s_setprio(0);
        }
      }
      if (more) {
#pragma unroll
        for (int j = 0; j < 4; ++j)
          *(bf16x8*)&Kl[cur ^ 1][(srow + 32 * j) * 72 + scol] = nk[j];
#pragma unroll
        for (int j = 0; j < 2; ++j)
#pragma unroll
          for (int k = 0; k < 2; ++k)
            *(bf16x8*)&Vl[cur ^ 1][(srow + 32 * j) * 136 + scol + 64 * k] = nv[j * 2 + k];
      }
      __syncthreads();
      cur ^= 1;
    }

    const float ltot = lrun + __shfl_xor(lrun, 32);
    const float inv = 1.f / ltot;
    const size_t rowb = ((size_t)(bh >> 4) * T_ + qb + q5) * DEMB_ + (bh & 15) * HD_;
#pragma unroll
    for (int g = 0; g < 4; ++g) {
      bf16x4 st0, st1;
#pragma unroll
      for (int j = 0; j < 4; ++j) {
        st0[j] = tob(o0[4 * g + j] * inv);
        st1[j] = tob(o1[4 * g + j] * inv);
      }
      *(bf16x4*)&ob[rowb + 8 * g + 4 * hi]      = st0;
      *(bf16x4*)&ob[rowb + 8 * g + 4 * hi + 32] = st1;
    }
  }
}

// ---------------- GEMM2: 128x128 tile, BK=64, single-buffer, row-XOR swizzled LDS ----------------
__global__ __launch_bounds__(256, 3) void gemm_out_kernel(const bf16_t* __restrict__ A,
                                                          const bf16_t* __restrict__ Bm,
                                                          const float* __restrict__ bo,
                                                          float* __restrict__ out) {
  constexpr int K = DEMB_;
  __shared__ __align__(16) bf16_t As[128 * 64];
  __shared__ __align__(16) bf16_t Bs[128 * 64];
  const int tid = threadIdx.x, w = tid >> 6, l = tid & 63;
  const int lh = l >> 4, lr = l & 15;
  const int m0 = blockIdx.y * 128, n0 = blockIdx.x * 128;
  const int ar0 = (w >> 1) * 64, bc0 = (w & 1) * 64;
  f32x4 acc[4][4] = {};
  for (int k0 = 0; k0 < K; k0 += 64) {
#pragma unroll
    for (int i = 0; i < 4; ++i) {
      const int jx = i * 256 + tid;
      const int row = jx >> 3, us = (jx & 7) ^ (row & 7);
      gload16(A  + (size_t)(m0 + row) * K + k0 + us * 8, (char*)As + (size_t)(i * 256 + w * 64) * 16);
      gload16(Bm + (size_t)(n0 + row) * K + k0 + us * 8, (char*)Bs + (size_t)(i * 256 + w * 64) * 16);
    }
    __syncthreads();
#pragma unroll
    for (int kk = 0; kk < 2; ++kk) {
      bf16x8 af[4], bfv[4];
#pragma unroll
      for (int mi = 0; mi < 4; ++mi) {
        const int r = ar0 + mi * 16 + lr;
        af[mi] = *(const bf16x8*)&As[r * 64 + (((kk * 4 + lh) ^ (r & 7)) * 8)];
      }
#pragma unroll
      for (int ni = 0; ni < 4; ++ni) {
        const int r = bc0 + ni * 16 + lr;
        bfv[ni] = *(const bf16x8*)&Bs[r * 64 + (((kk * 4 + lh) ^ (r & 7)) * 8)];
      }
      __builtin_amdgcn_s_setprio(1);
#pragma unroll
      for (int mi = 0; mi < 4; ++mi)
#pragma unroll
        for (int ni = 0; ni < 4; ++ni)
          acc[mi][ni] = mfma16(af[mi], bfv[ni], acc[mi][ni]);
      __builtin_amdgcn_s_setprio(0);
    }
    __syncthreads();
  }
#pragma unroll
  for (int mi = 0; mi < 4; ++mi) {
#pragma unroll
    for (int r = 0; r < 4; ++r) {
      const int gm = m0 + ar0 + mi * 16 + lh * 4 + r;
#pragma unroll
      for (int ni = 0; ni < 4; ++ni) {
        const int gn = n0 + bc0 + ni * 16 + lr;
        out[(size_t)gm * DEMB_ + gn] = acc[mi][ni][r] + bo[gn];
      }
    }
  }
}

extern "C" void kernel_launch(void* const* d_in, const int* in_sizes, int n_in,
                              void* d_out, int out_size, void* d_ws, size_t ws_size,
                              hipStream_t stream) {
  (void)in_sizes; (void)n_in; (void)out_size; (void)ws_size;
  const float* x     = (const float*)d_in[0];
  const float* w_qkv = (const float*)d_in[1];
  const float* w_o   = (const float*)d_in[2];
  const float* b_o   = (const float*)d_in[3];
  float* out = (float*)d_out;

  // Round-1-proven 75.5 MB workspace layout; vbuf holds V^T [B,H,64,T].
  char* p = (char*)d_ws;
  bf16_t* xb    = (bf16_t*)p; p += (size_t)M_ * DIN_ * 2;
  bf16_t* wqkvb = (bf16_t*)p; p += (size_t)NQKV_ * DIN_ * 2;
  bf16_t* wob   = (bf16_t*)p; p += (size_t)DEMB_ * DEMB_ * 2;
  bf16_t* qbuf  = (bf16_t*)p; p += (size_t)B_ * H_ * T_ * HD_ * 2;
  bf16_t* kbuf  = (bf16_t*)p; p += (size_t)B_ * H_ * T_ * HD_ * 2;
  bf16_t* vbuf  = (bf16_t*)p; p += (size_t)B_ * H_ * T_ * HD_ * 2;
  bf16_t* attnb = xb;    // x dead after gemm1

  constexpr int CAST_BLOCKS = (M_ * DIN_ + NQKV_ * DIN_ + DEMB_ * DEMB_) / 1024;  // 12288
  cast3_kernel<<<CAST_BLOCKS, 256, 0, stream>>>(x, xb, w_qkv, wqkvb, w_o, wob);
  gemm_qkv_kernel<<<dim3(NQKV_ / 128, M_ / 128), 256, 0, stream>>>(xb, wqkvb, qbuf, kbuf, vbuf);
  attn2_kernel<<<512, 256, 0, stream>>>(qbuf, kbuf, vbuf, attnb);
  gemm_out_kernel<<<dim3(DEMB_ / 128, M_ / 128), 256, 0, stream>>>(attnb, wob, b_o, out);
}